// Round 1
// baseline (416.059 us; speedup 1.0000x reference)
//
#include <hip/hip_runtime.h>

// Problem constants (from reference):
//   HOP = 512, SEG = 1024, BATCH = 16, NUM_SAMPLES = 4194304
//   num_segments K = (N - SEG)/HOP + 1 = 8191
//
// Math: out[b,n] = x[b,n] * g(n),
//   g(n) = (k <= K-1 ? aw[r]*sw[r] : 0) + (k >= 1 ? aw[r+512]*sw[r+512] : 0)
//   where r = n & 511, k = n >> 9.
// Interior gain is exactly aw[r]*sw[r] + aw[r+512]*sw[r+512] (==1 for sqrt-Hann
// WOLA); only the first and last 512 samples of each row differ.

constexpr int HOP   = 512;
constexpr int SEG   = 1024;
constexpr long long NSAMP = 4194304;       // power of two -> mask for row index
constexpr int KSEG  = (int)((NSAMP - SEG) / HOP + 1);  // 8191

__global__ __launch_bounds__(256) void wola_gain_kernel(
    const float* __restrict__ x,
    const float* __restrict__ aw,
    const float* __restrict__ sw,
    float* __restrict__ out,
    long long n4)  // number of float4 elements
{
    long long i = (long long)blockIdx.x * blockDim.x + threadIdx.x;
    if (i >= n4) return;

    long long e = i << 2;                 // flat element index (b*N + n), %4 == 0
    int n = (int)(e & (NSAMP - 1));       // index within row (N is 2^22)
    int r = n & (HOP - 1);                // phase within hop; r%4==0
    int k = n >> 9;                       // frame index for s=r

    const float4 xv = reinterpret_cast<const float4*>(x)[i];
    // Window loads: 16B aligned (r%4==0, HOP%4==0); tiny footprint, L1-resident.
    const float4 a0 = reinterpret_cast<const float4*>(aw)[r >> 2];
    const float4 s0 = reinterpret_cast<const float4*>(sw)[r >> 2];
    const float4 a1 = reinterpret_cast<const float4*>(aw)[(r + HOP) >> 2];
    const float4 s1 = reinterpret_cast<const float4*>(sw)[(r + HOP) >> 2];

    // s=r contribution valid iff its frame k <= K-1 (fails only for last 512/row)
    const float m0 = (k <= KSEG - 1) ? 1.0f : 0.0f;
    // s=r+512 contribution valid iff frame k-1 >= 0 (fails only for first 512/row);
    // upper bound k-1 <= K-1 always holds since max k = (N-1)>>9 = 8191 = K.
    const float m1 = (k >= 1) ? 1.0f : 0.0f;

    float4 o;
    o.x = xv.x * (m0 * (a0.x * s0.x) + m1 * (a1.x * s1.x));
    o.y = xv.y * (m0 * (a0.y * s0.y) + m1 * (a1.y * s1.y));
    o.z = xv.z * (m0 * (a0.z * s0.z) + m1 * (a1.z * s1.z));
    o.w = xv.w * (m0 * (a0.w * s0.w) + m1 * (a1.w * s1.w));

    reinterpret_cast<float4*>(out)[i] = o;
}

extern "C" void kernel_launch(void* const* d_in, const int* in_sizes, int n_in,
                              void* d_out, int out_size, void* d_ws, size_t ws_size,
                              hipStream_t stream) {
    const float* x  = (const float*)d_in[0];   // [16, 4194304] f32
    const float* aw = (const float*)d_in[1];   // [1024] f32
    const float* sw = (const float*)d_in[2];   // [1024] f32
    float* out = (float*)d_out;                // [16, 4194304] f32

    const long long total = (long long)out_size;   // 67108864
    const long long n4 = total >> 2;               // 16777216 float4s
    const int block = 256;
    const long long grid = (n4 + block - 1) / block;  // 65536

    wola_gain_kernel<<<(unsigned)grid, block, 0, stream>>>(x, aw, sw, out, n4);
}